// Round 7
// baseline (1404.993 us; speedup 1.0000x reference)
//
#include <hip/hip_runtime.h>
#include <math.h>

// Problem constants
#define TT    48
#define BB    96
#define DG    192
#define DH    384
#define NSTEP 47     // T-1 scan steps
#define SETI  3      // inner settling iterations

typedef unsigned short ushort_t;

__device__ __forceinline__ float blo(unsigned u) {
  return __uint_as_float(u << 16);
}
__device__ __forceinline__ float bhi(unsigned u) {
  return __uint_as_float(u & 0xFFFF0000u);
}

__device__ __forceinline__ float wred(float v) {
#pragma unroll
  for (int off = 32; off; off >>= 1) v += __shfl_xor(v, off, 64);
  return v;
}
__device__ __forceinline__ void wred2(float& a, float& b) {
#pragma unroll
  for (int off = 32; off; off >>= 1) {
    a += __shfl_xor(a, off, 64);
    b += __shfl_xor(b, off, 64);
  }
}
__device__ __forceinline__ void wred3(float& a, float& b, float& c) {
#pragma unroll
  for (int off = 32; off; off >>= 1) {
    a += __shfl_xor(a, off, 64);
    b += __shfl_xor(b, off, 64);
    c += __shfl_xor(c, off, 64);
  }
}
__device__ __forceinline__ void wred5(float& a, float& b, float& c, float& d,
                                      float& e) {
#pragma unroll
  for (int off = 32; off; off >>= 1) {
    a += __shfl_xor(a, off, 64);
    b += __shfl_xor(b, off, 64);
    c += __shfl_xor(c, off, 64);
    d += __shfl_xor(d, off, 64);
    e += __shfl_xor(e, off, 64);
  }
}

// ====================== MAIN: one wave per batch element ======================
// Component mapping: hidden index j = 64*k + l, lane l holds k = 0..5.
// Wt packed fp32: float2 at [j*192 + kp*64 + l] = ( W_h[128*kp +    l][j],
//                                                   W_h[128*kp + 64+l][j] )
// XZp packed bf16 pairs: uint at [row*192 + kp*64 + l] = comps (128kp+l, 128kp+64+l)
// of (W_g z + b_h), row = t*BB + b.
// No __syncthreads anywhere: all reductions are wave-internal shuffles; all
// LDS traffic is same-wave (lockstep) with stride-64 conflict-free patterns.
__global__ __launch_bounds__(64) void fw_rnn_wave(
    const unsigned* __restrict__ XZp,  // [T*B][192] bf16-pair-packed
    const float* __restrict__ Wt,      // [DH][3][64] float2-packed transpose
    const float* __restrict__ ln_g,
    const float* __restrict__ ln_b,
    const float* __restrict__ alpha_fw,
    float* __restrict__ out)           // [B, DH]
{
  __shared__ float hist[NSTEP * DH];   // h_0..h_46, natural j order
  __shared__ float wlam[NSTEP];        // eta * lam^(age)

  const int l = threadIdx.x;           // 0..63
  const int b = blockIdx.x;

  float g_r[6], be_r[6];
#pragma unroll
  for (int k = 0; k < 6; ++k) {
    g_r[k]  = ln_g[64 * k + l];
    be_r[k] = ln_b[64 * k + l];
  }

  const float af   = alpha_fw[0];
  const float kcur = (af >= 0.f) ? (1.f + log1pf(expf(af)))
                                 : (1.f / (1.f + log1pf(expf(-af))));
  const float invD = 1.0f / (float)DH;

  float hsr[6];

  for (int t = 0; t <= NSTEP; ++t) {   // t == NSTEP is the query step
    const bool fin = (t == NSTEP);

    // ---- h_base init from XZ (bf16 pairs) ----
    float hb[6];
    {
      const unsigned* xzr = XZp + (size_t)(t * BB + b) * 192;
      unsigned u0 = xzr[l], u1 = xzr[64 + l], u2 = xzr[128 + l];
      hb[0] = blo(u0); hb[1] = bhi(u0);
      hb[2] = blo(u1); hb[3] = bhi(u1);
      hb[4] = blo(u2); hb[5] = bhi(u2);
    }

    // ---- h_base += W_h h_{t-1} : fp32 Wt stream from L2, coalesced ----
    if (t > 0) {
      const float* hprev = hist + (size_t)(t - 1) * DH;
      const float2* wt2  = (const float2*)Wt;
#pragma unroll 2
      for (int jb = 0; jb < DH; jb += 4) {
        float4 h4 = *(const float4*)(hprev + jb);  // LDS broadcast
#pragma unroll
        for (int q = 0; q < 4; ++q) {
          const float hj = (q == 0) ? h4.x : (q == 1) ? h4.y
                         : (q == 2) ? h4.z : h4.w;
          const float2* wp = wt2 + (size_t)(jb + q) * 192 + l;
          float2 w0 = wp[0], w1 = wp[64], w2 = wp[128];
          hb[0] = fmaf(w0.x, hj, hb[0]); hb[1] = fmaf(w0.y, hj, hb[1]);
          hb[2] = fmaf(w1.x, hj, hb[2]); hb[3] = fmaf(w1.y, hj, hb[3]);
          hb[4] = fmaf(w2.x, hj, hb[4]); hb[5] = fmaf(w2.y, hj, hb[5]);
        }
      }
    }

    // ---- base LN + ReLU ----
    float s1 = 0.f, s2 = 0.f;
#pragma unroll
    for (int k = 0; k < 6; ++k) { s1 += hb[k]; s2 += hb[k] * hb[k]; }
    wred2(s1, s2);
    const float Shb = s1, Shb2 = s2;
    {
      float m   = s1 * invD;
      float var = s2 * invD - m * m;
      float rs  = rsqrtf(var + 1e-5f);
#pragma unroll
      for (int k = 0; k < 6; ++k)
        hsr[k] = fmaxf((hb[k] - m) * rs * g_r[k] + be_r[k], 0.f);
    }

    // ---- settling (skipped at t==0: A == 0) ----
    const int hlen = fin ? NSTEP : t;
    if (hlen > 0) {
      for (int s = 0; s < SETI; ++s) {
        float Ah[6] = {0.f, 0.f, 0.f, 0.f, 0.f, 0.f};
        int tau = 0;
        for (; tau + 1 < hlen; tau += 2) {   // 2-way interleaved reduces
          const float* h0 = hist + (size_t)tau * DH;
          const float* h1 = h0 + DH;
          float hv0[6], hv1[6];
          float p0 = 0.f, p1 = 0.f;
#pragma unroll
          for (int k = 0; k < 6; ++k) {
            hv0[k] = h0[64 * k + l]; p0 = fmaf(hv0[k], hsr[k], p0);
            hv1[k] = h1[64 * k + l]; p1 = fmaf(hv1[k], hsr[k], p1);
          }
          wred2(p0, p1);
          float d0 = p0 * wlam[tau], d1 = p1 * wlam[tau + 1];
#pragma unroll
          for (int k = 0; k < 6; ++k) {
            Ah[k] = fmaf(d0, hv0[k], Ah[k]);
            Ah[k] = fmaf(d1, hv1[k], Ah[k]);
          }
        }
        if (tau < hlen) {
          const float* h0 = hist + (size_t)tau * DH;
          float hv0[6];
          float p0 = 0.f;
#pragma unroll
          for (int k = 0; k < 6; ++k) {
            hv0[k] = h0[64 * k + l]; p0 = fmaf(hv0[k], hsr[k], p0);
          }
          p0 = wred(p0);
          float d0 = p0 * wlam[tau];
#pragma unroll
          for (int k = 0; k < 6; ++k) Ah[k] = fmaf(d0, hv0[k], Ah[k]);
        }

        if (!fin) {
          // cosine gate + analytic LN (xv = beta*hb + a*Ah)
          float v0 = 0, v1 = 0, v2 = 0, v3 = 0, v4 = 0;
#pragma unroll
          for (int k = 0; k < 6; ++k) {
            v0 += hsr[k] * Ah[k]; v1 += hsr[k] * hsr[k]; v2 += Ah[k] * Ah[k];
            v3 += hb[k] * Ah[k];  v4 += Ah[k];
          }
          wred5(v0, v1, v2, v3, v4);
          float n1 = fmaxf(sqrtf(v1), 1e-6f);
          float n2 = fmaxf(sqrtf(v2), 1e-6f);
          float R  = fminf(fmaxf(v0 / (n1 * n2), 0.f), 1.f);
          float a  = 1.f - powf(1.f - R, kcur);
          float beta = 1.f - a * a;
          float mu  = (beta * Shb + a * v4) * invD;
          float Exx = (beta * beta * Shb2 + 2.f * beta * a * v3 + a * a * v2)
                      * invD;
          float var = Exx - mu * mu;
          float rs  = rsqrtf(var + 1e-5f);
#pragma unroll
          for (int k = 0; k < 6; ++k) {
            float xv = beta * hb[k] + a * Ah[k];
            hsr[k] = fmaxf((xv - mu) * rs * g_r[k] + be_r[k], 0.f);
          }
        } else {
          // query step: xv = hb + Ah, no gate
          float v2 = 0, v3 = 0, v4 = 0;
#pragma unroll
          for (int k = 0; k < 6; ++k) {
            v2 += Ah[k] * Ah[k]; v3 += hb[k] * Ah[k]; v4 += Ah[k];
          }
          wred3(v2, v3, v4);
          float Sx  = Shb + v4;
          float Sxx = Shb2 + 2.f * v3 + v2;
          float mu  = Sx * invD;
          float var = Sxx * invD - mu * mu;
          float rs  = rsqrtf(var + 1e-5f);
#pragma unroll
          for (int k = 0; k < 6; ++k) {
            float xv = hb[k] + Ah[k];
            hsr[k] = fmaxf((xv - mu) * rs * g_r[k] + be_r[k], 0.f);
          }
        }
      }
    }

    // ---- commit h_t, update decay weights (wave-internal, no barrier) ----
    if (!fin) {
#pragma unroll
      for (int k = 0; k < 6; ++k) hist[(size_t)t * DH + 64 * k + l] = hsr[k];
      if (l < t) wlam[l] *= 0.9f;
      if (l == t) wlam[l] = 0.5f;
      __builtin_amdgcn_wave_barrier();  // pin compiler ordering (free)
    }
  }

#pragma unroll
  for (int k = 0; k < 6; ++k) out[(size_t)b * DH + 64 * k + l] = hsr[k];
}

// ====================== PRE-PASSES ======================

// Pack W_h into lane-major transposed fp32 layout:
// Wt_float2[j*192 + kp*64 + l] = ( W[128kp+l][j], W[128kp+64+l][j] )
__global__ void pack_w_kernel(const float* __restrict__ W_h,
                              float* __restrict__ Wt) {
  int n = blockIdx.x * 256 + threadIdx.x;     // n = r*384 + j (coalesced read)
  if (n >= DH * DH) return;
  int r = n / DH, j = n % DH;
  int k = r >> 6, ll = r & 63, kp = k >> 1, comp = k & 1;
  Wt[(size_t)(j * 192 + kp * 64 + ll) * 2 + comp] = W_h[n];
}

// XZ[t,b,:] = W_g z[t,b] + b_h, written as bf16 pairs in the packed layout.
__global__ __launch_bounds__(512) void xz_kernel(
    const float* __restrict__ z_seq, const float* __restrict__ W_g,
    const float* __restrict__ b_h, ushort_t* __restrict__ XZ)
{
  __shared__ float zs[8 * DG];
  const int tid = threadIdx.x;
  const int t = blockIdx.x, b0 = blockIdx.y * 8;
  const int g = tid >> 4, lane16 = tid & 15;

  const float4* src = (const float4*)(z_seq + ((size_t)t * BB + b0) * DG);
  if (tid < 8 * DG / 4) ((float4*)zs)[tid] = src[tid];
  __syncthreads();

#pragma unroll 2
  for (int p = 0; p < 12; ++p) {
    const int r = p * 32 + g;
    const float4* wr = (const float4*)(W_g + (size_t)r * DG);
    float4 w[3];
#pragma unroll
    for (int c = 0; c < 3; ++c) w[c] = wr[lane16 + 16 * c];
    float acc[8];
#pragma unroll
    for (int bb = 0; bb < 8; ++bb) acc[bb] = 0.f;
#pragma unroll
    for (int bb = 0; bb < 8; ++bb) {
      const float4* zz = (const float4*)(zs + bb * DG);
#pragma unroll
      for (int c = 0; c < 3; ++c) {
        float4 z = zz[lane16 + 16 * c];
        acc[bb] = fmaf(w[c].x, z.x, acc[bb]);
        acc[bb] = fmaf(w[c].y, z.y, acc[bb]);
        acc[bb] = fmaf(w[c].z, z.z, acc[bb]);
        acc[bb] = fmaf(w[c].w, z.w, acc[bb]);
      }
    }
#pragma unroll
    for (int bb = 0; bb < 8; ++bb) {
      acc[bb] += __shfl_xor(acc[bb], 8, 64);
      acc[bb] += __shfl_xor(acc[bb], 4, 64);
      acc[bb] += __shfl_xor(acc[bb], 2, 64);
      acc[bb] += __shfl_xor(acc[bb], 1, 64);
    }
    if (lane16 == 0) {
      const int k = r >> 6, ll = r & 63, kp = k >> 1, comp = k & 1;
      float bh = b_h[r];
#pragma unroll
      for (int bb = 0; bb < 8; ++bb) {
        float v = acc[bb] + bh;
        unsigned u = __float_as_uint(v);
        unsigned rr = (u + 0x7FFFu + ((u >> 16) & 1u)) >> 16;  // RTN-even
        XZ[((size_t)(t * BB + b0 + bb) * 192 + kp * 64 + ll) * 2 + comp] =
            (ushort_t)rr;
      }
    }
  }
}

// ====================== FALLBACK (ws too small; never expected) ======================
__global__ __launch_bounds__(384) void fw_rnn_basic(
    const float* __restrict__ z_seq, const float* __restrict__ W_h,
    const float* __restrict__ W_g, const float* __restrict__ b_h,
    const float* __restrict__ ln_g, const float* __restrict__ ln_b,
    const float* __restrict__ alpha_fw, float* __restrict__ out)
{
  __shared__ float hist[NSTEP * DH];
  __shared__ float hs[DH];
  __shared__ float zsh[DG];
  __shared__ float wlamS[NSTEP];
  __shared__ float carr[NSTEP];
  __shared__ float red[6 * 3];

  const int tid = threadIdx.x, b = blockIdx.x;
  const int lane = tid & 63, wv = tid >> 6;
  const float bh_i = b_h[tid], g_i = ln_g[tid], be_i = ln_b[tid];
  const float af = alpha_fw[0];
  const float kk = (af >= 0.f) ? (1.f + log1pf(expf(af)))
                               : (1.f / (1.f + log1pf(expf(-af))));
  const float invD = 1.0f / (float)DH;

  for (int t = 0; t <= NSTEP; ++t) {
    if (tid < DG / 4)
      ((float4*)zsh)[tid] =
          ((const float4*)(z_seq + ((size_t)t * BB + b) * DG))[tid];
    __syncthreads();
    float hb = bh_i;
    {
      const float4* wg4 = (const float4*)(W_g + (size_t)tid * DG);
      const float4* z4 = (const float4*)zsh;
      for (int j = 0; j < DG / 4; ++j) {
        float4 w = wg4[j], z = z4[j];
        hb = fmaf(w.x, z.x, hb); hb = fmaf(w.y, z.y, hb);
        hb = fmaf(w.z, z.z, hb); hb = fmaf(w.w, z.w, hb);
      }
    }
    if (t > 0) {
      const float4* wh4 = (const float4*)(W_h + (size_t)tid * DH);
      const float4* hp4 = (const float4*)(hist + (size_t)(t - 1) * DH);
      for (int j = 0; j < DH / 4; ++j) {
        float4 w = wh4[j], h = hp4[j];
        hb = fmaf(w.x, h.x, hb); hb = fmaf(w.y, h.y, hb);
        hb = fmaf(w.z, h.z, hb); hb = fmaf(w.w, h.w, hb);
      }
    }
    float v0 = hb, v1 = hb * hb;
#pragma unroll
    for (int off = 32; off; off >>= 1) {
      v0 += __shfl_xor(v0, off, 64); v1 += __shfl_xor(v1, off, 64);
    }
    if (lane == 0) { red[wv * 3] = v0; red[wv * 3 + 1] = v1; }
    __syncthreads();
    float S1 = 0, S2 = 0;
    for (int w = 0; w < 6; ++w) { S1 += red[w * 3]; S2 += red[w * 3 + 1]; }
    float m = S1 * invD, var = S2 * invD - m * m;
    float hv = fmaxf((hb - m) * rsqrtf(var + 1e-5f) * g_i + be_i, 0.f);
    hs[tid] = hv;
    __syncthreads();
    int hlen = (t == NSTEP) ? NSTEP : t;
    if (hlen > 0) {
      for (int s = 0; s < SETI; ++s) {
        if (tid < hlen) {
          float p = 0.f;
          for (int j = 0; j < DH; ++j)
            p = fmaf(hist[(size_t)tid * DH + j], hs[j], p);
          carr[tid] = p * wlamS[tid];
        }
        __syncthreads();
        float ah = 0.f;
        for (int tau = 0; tau < hlen; ++tau)
          ah = fmaf(carr[tau], hist[(size_t)tau * DH + tid], ah);
        float w0 = hv * ah, w1 = hv * hv, w2 = ah * ah;
#pragma unroll
        for (int off = 32; off; off >>= 1) {
          w0 += __shfl_xor(w0, off, 64);
          w1 += __shfl_xor(w1, off, 64);
          w2 += __shfl_xor(w2, off, 64);
        }
        if (lane == 0) {
          red[wv * 3] = w0; red[wv * 3 + 1] = w1; red[wv * 3 + 2] = w2;
        }
        __syncthreads();
        float T0 = 0, T1 = 0, T2 = 0;
        for (int w = 0; w < 6; ++w) {
          T0 += red[w * 3]; T1 += red[w * 3 + 1]; T2 += red[w * 3 + 2];
        }
        float xv;
        if (t < NSTEP) {
          float n1 = fmaxf(sqrtf(T1), 1e-6f), n2 = fmaxf(sqrtf(T2), 1e-6f);
          float R = fminf(fmaxf(T0 / (n1 * n2), 0.f), 1.f);
          float a = 1.f - powf(1.f - R, kk);
          xv = (1.f - a * a) * hb + a * ah;
        } else {
          xv = hb + ah;
        }
        __syncthreads();
        float u0 = xv, u1 = xv * xv;
#pragma unroll
        for (int off = 32; off; off >>= 1) {
          u0 += __shfl_xor(u0, off, 64); u1 += __shfl_xor(u1, off, 64);
        }
        if (lane == 0) { red[wv * 3] = u0; red[wv * 3 + 1] = u1; }
        __syncthreads();
        float X1 = 0, X2 = 0;
        for (int w = 0; w < 6; ++w) { X1 += red[w * 3]; X2 += red[w * 3 + 1]; }
        float mm = X1 * invD, vv = X2 * invD - mm * mm;
        hv = fmaxf((xv - mm) * rsqrtf(vv + 1e-5f) * g_i + be_i, 0.f);
        hs[tid] = hv;
        __syncthreads();
      }
    }
    if (t < NSTEP) {
      hist[(size_t)t * DH + tid] = hv;
      if (tid < t) wlamS[tid] *= 0.9f;
      if (tid == t) wlamS[tid] = 0.5f;
      __syncthreads();
    } else {
      out[(size_t)b * DH + tid] = hv;
    }
  }
}

extern "C" void kernel_launch(void* const* d_in, const int* in_sizes, int n_in,
                              void* d_out, int out_size, void* d_ws, size_t ws_size,
                              hipStream_t stream) {
  const float* z_seq    = (const float*)d_in[0];
  const float* W_h      = (const float*)d_in[1];
  const float* W_g      = (const float*)d_in[2];
  const float* b_h      = (const float*)d_in[3];
  const float* ln_g     = (const float*)d_in[4];
  const float* ln_b     = (const float*)d_in[5];
  const float* alpha_fw = (const float*)d_in[6];
  float* out = (float*)d_out;

  const size_t nXZ = (size_t)TT * BB * DH;   // 1769472 bf16 elems
  const size_t nWt = (size_t)DH * DH;        // 147456 fp32 elems
  const size_t need = nXZ * sizeof(ushort_t) + nWt * sizeof(float);  // ~4.1 MB

  if (ws_size >= need) {
    ushort_t* XZ = (ushort_t*)d_ws;
    float* Wt = (float*)((char*)d_ws + nXZ * sizeof(ushort_t));
    pack_w_kernel<<<dim3((int)((nWt + 255) / 256)), dim3(256), 0, stream>>>(
        W_h, Wt);
    xz_kernel<<<dim3(TT, BB / 8), dim3(512), 0, stream>>>(z_seq, W_g, b_h, XZ);
    fw_rnn_wave<<<dim3(BB), dim3(64), 0, stream>>>(
        (const unsigned*)XZ, Wt, ln_g, ln_b, alpha_fw, out);
  } else {
    fw_rnn_basic<<<dim3(BB), dim3(DH), 0, stream>>>(
        z_seq, W_h, W_g, b_h, ln_g, ln_b, alpha_fw, out);
  }
}

// Round 8
// 818.236 us; speedup vs baseline: 1.7171x; 1.7171x over previous
//
#include <hip/hip_runtime.h>
#include <math.h>

// Problem constants
#define TT    48
#define BB    96
#define DG    192
#define DH    384
#define NSTEP 47     // T-1 scan steps
#define SETI  3      // inner settling iterations
#define NT    384    // 6 waves; thread i owns hidden element i
#define NW    6

typedef unsigned short ushort_t;

__device__ __forceinline__ float blo(unsigned u) {
  return __uint_as_float(u << 16);
}
__device__ __forceinline__ float bhi(unsigned u) {
  return __uint_as_float(u & 0xFFFF0000u);
}

__device__ __forceinline__ float wred(float v) {
#pragma unroll
  for (int off = 32; off; off >>= 1) v += __shfl_xor(v, off, 64);
  return v;
}

// ====================== MAIN ======================
// Thread i owns hidden element i. 6 waves.
// Wp: bf16-pair-packed W_h^T: Wp[j2*DH + i] = ( W_h[i][2*j2], W_h[i][2*j2+1] ).
// Matvec: thread i streams column i of Wp (coalesced 256B/inst across the
// wave), h_prev via LDS broadcast reads. No cross-lane reduce in the matvec.
// All LDS access patterns are (lane + 64c) -> bank = lane%32, 2 lanes/bank =
// conflict-free (m136). hist unpadded [tau][i].
__global__ __launch_bounds__(NT) void fw_rnn_v8(
    const float* __restrict__ XZ,      // [T*B][DH] = W_g z + b_h  (fp32)
    const unsigned* __restrict__ Wp,   // [DG2=192][DH] bf16-pair packed W^T
    const float* __restrict__ ln_g,
    const float* __restrict__ ln_b,
    const float* __restrict__ alpha_fw,
    float* __restrict__ out)           // [B, DH]
{
  __shared__ float hist[NSTEP * DH];   // h_0..h_46
  __shared__ float hs[DH];             // current settling state
  __shared__ float wlam[NSTEP + 1];    // eta * lam^(age)
  __shared__ float carr[NSTEP + 1];    // weighted dots
  __shared__ float redA[NW * 2];       // base-LN partials
  __shared__ float redB[NW * 5];       // settle partials

  const int tid  = threadIdx.x;        // 0..383
  const int b    = blockIdx.x;
  const int lane = tid & 63, wv = tid >> 6;

  const float g_i  = ln_g[tid];
  const float be_i = ln_b[tid];
  const float af   = alpha_fw[0];
  const float kcur = (af >= 0.f) ? (1.f + log1pf(expf(af)))
                                 : (1.f / (1.f + log1pf(expf(-af))));
  const float invD = 1.0f / (float)DH;

  for (int t = 0; t <= NSTEP; ++t) {   // t == NSTEP is the query step
    const bool fin = (t == NSTEP);

    // ---------- h_base[i] = XZ row + W_h h_{t-1} (thread-local) ----------
    float hb = XZ[(size_t)(t * BB + b) * DH + tid];
    if (t > 0) {
      const float* hp = hist + (size_t)(t - 1) * DH;
      float a0 = 0.f, a1 = 0.f, a2 = 0.f, a3 = 0.f;
#pragma unroll 4
      for (int j2 = 0; j2 < DG; j2 += 4) {   // 4 pairs = 8 h values / iter
        unsigned w0 = Wp[(size_t)(j2 + 0) * DH + tid];
        unsigned w1 = Wp[(size_t)(j2 + 1) * DH + tid];
        unsigned w2 = Wp[(size_t)(j2 + 2) * DH + tid];
        unsigned w3 = Wp[(size_t)(j2 + 3) * DH + tid];
        float4 ha = *(const float4*)(hp + 2 * j2);      // broadcast
        float4 hbv = *(const float4*)(hp + 2 * j2 + 4); // broadcast
        a0 = fmaf(blo(w0), ha.x, a0);  a0 = fmaf(bhi(w0), ha.y, a0);
        a1 = fmaf(blo(w1), ha.z, a1);  a1 = fmaf(bhi(w1), ha.w, a1);
        a2 = fmaf(blo(w2), hbv.x, a2); a2 = fmaf(bhi(w2), hbv.y, a2);
        a3 = fmaf(blo(w3), hbv.z, a3); a3 = fmaf(bhi(w3), hbv.w, a3);
      }
      hb += (a0 + a1) + (a2 + a3);
    }

    // ---------- base LN stats (fused; hb never leaves registers) ----------
    {
      float v0 = hb, v1 = hb * hb;
#pragma unroll
      for (int off = 32; off; off >>= 1) {
        v0 += __shfl_xor(v0, off, 64);
        v1 += __shfl_xor(v1, off, 64);
      }
      if (lane == 0) { redA[wv * 2] = v0; redA[wv * 2 + 1] = v1; }
    }
    __syncthreads();  // (1) redA visible

    float Shb = 0.f, Shb2 = 0.f;
#pragma unroll
    for (int w = 0; w < NW; ++w) { Shb += redA[w * 2]; Shb2 += redA[w * 2 + 1]; }
    float hsv;
    {
      float m   = Shb * invD;
      float var = Shb2 * invD - m * m;
      hsv = fmaxf((hb - m) * rsqrtf(var + 1e-5f) * g_i + be_i, 0.f);
      hs[tid] = hsv;
    }

    if (t == 0) {
      hist[tid] = hsv;
      if (tid == 0) wlam[0] = 0.5f;
      __syncthreads();  // (2) hist/wlam visible for step 1
      continue;
    }
    __syncthreads();  // (2) hs visible

    // ---------- settling ----------
    const int hlen = fin ? NSTEP : t;
    for (int s = 0; s < SETI; ++s) {
      // phase A: d_tau = wlam_tau * (h_tau . h_s); wave wv takes taus wv,wv+6,..
      for (int tau = wv; tau < hlen; tau += NW) {
        const float* hr = hist + (size_t)tau * DH;
        float p = 0.f;
#pragma unroll
        for (int c = 0; c < NW; ++c)
          p = fmaf(hr[64 * c + lane], hs[64 * c + lane], p);
        p = wred(p);
        if (lane == 0) carr[tau] = p * wlam[tau];
      }
      __syncthreads();  // (i) carr visible

      // phase B: Ah[i] + 5 block sums
      float ah;
      {
        float a0 = 0.f, a1 = 0.f;
        int tau = 0;
        for (; tau + 1 < hlen; tau += 2) {
          a0 = fmaf(carr[tau], hist[(size_t)tau * DH + tid], a0);
          a1 = fmaf(carr[tau + 1], hist[(size_t)(tau + 1) * DH + tid], a1);
        }
        if (tau < hlen) a0 = fmaf(carr[tau], hist[(size_t)tau * DH + tid], a0);
        ah = a0 + a1;
      }
      {
        float v0 = hsv * ah, v1 = hsv * hsv, v2 = ah * ah, v3 = hb * ah, v4 = ah;
#pragma unroll
        for (int off = 32; off; off >>= 1) {
          v0 += __shfl_xor(v0, off, 64);
          v1 += __shfl_xor(v1, off, 64);
          v2 += __shfl_xor(v2, off, 64);
          v3 += __shfl_xor(v3, off, 64);
          v4 += __shfl_xor(v4, off, 64);
        }
        if (lane == 0) {
          redB[wv * 5 + 0] = v0; redB[wv * 5 + 1] = v1; redB[wv * 5 + 2] = v2;
          redB[wv * 5 + 3] = v3; redB[wv * 5 + 4] = v4;
        }
      }
      __syncthreads();  // (ii) redB visible

      // phase C: gate + analytic LN + publish hs
      {
        float S0 = 0, S1 = 0, S2 = 0, S3 = 0, S4 = 0;
#pragma unroll
        for (int w = 0; w < NW; ++w) {
          S0 += redB[w * 5 + 0]; S1 += redB[w * 5 + 1]; S2 += redB[w * 5 + 2];
          S3 += redB[w * 5 + 3]; S4 += redB[w * 5 + 4];
        }
        float xv, mu, var;
        if (!fin) {
          float n1 = fmaxf(sqrtf(S1), 1e-6f);
          float n2 = fmaxf(sqrtf(S2), 1e-6f);
          float R  = fminf(fmaxf(S0 / (n1 * n2), 0.f), 1.f);
          float a  = 1.f - powf(1.f - R, kcur);
          float beta = 1.f - a * a;
          mu  = (beta * Shb + a * S4) * invD;
          float Exx = (beta * beta * Shb2 + 2.f * beta * a * S3 + a * a * S2)
                      * invD;
          var = Exx - mu * mu;
          xv  = beta * hb + a * ah;
        } else {
          float Sx  = Shb + S4;
          float Sxx = Shb2 + 2.f * S3 + S2;
          mu  = Sx * invD;
          var = Sxx * invD - mu * mu;
          xv  = hb + ah;
        }
        hsv = fmaxf((xv - mu) * rsqrtf(var + 1e-5f) * g_i + be_i, 0.f);
        hs[tid] = hsv;
        if (!fin && s == SETI - 1) {
          hist[(size_t)t * DH + tid] = hsv;
          if (tid < t) wlam[tid] *= 0.9f;
          else if (tid == t) wlam[tid] = 0.5f;
        }
      }
      if (!fin || s < SETI - 1) __syncthreads();  // (iii)
    }
  }

  out[(size_t)b * DH + tid] = __shfl_xor(0.f, 0, 64) + hs[tid];  // hs == final
}

// ====================== PRE-PASSES ======================

// Wp[j2*DH + i] = bf16pair( W_h[i][2*j2], W_h[i][2*j2+1] ), RTN-even.
__global__ void pack_w_kernel(const float* __restrict__ W_h,
                              unsigned* __restrict__ Wp) {
  int n = blockIdx.x * 256 + threadIdx.x;   // n = j2*DH + i  (coalesced write)
  if (n >= (DG) * DH) return;
  int j2 = n / DH, i = n % DH;
  float a = W_h[(size_t)i * DH + 2 * j2];
  float c = W_h[(size_t)i * DH + 2 * j2 + 1];
  unsigned ua = __float_as_uint(a);
  unsigned uc = __float_as_uint(c);
  unsigned ra = (ua + 0x7FFFu + ((ua >> 16) & 1u)) >> 16;
  unsigned rc = (uc + 0x7FFFu + ((uc >> 16) & 1u)) >> 16;
  Wp[n] = (ra & 0xFFFFu) | (rc << 16);
}

// XZ[t,b,:] = W_g z[t,b] + b_h (fp32). Validated in rounds 4-6.
__global__ __launch_bounds__(512) void xz_kernel(
    const float* __restrict__ z_seq, const float* __restrict__ W_g,
    const float* __restrict__ b_h, float* __restrict__ XZ)
{
  __shared__ float zs[8 * DG];
  const int tid = threadIdx.x;
  const int t = blockIdx.x, b0 = blockIdx.y * 8;
  const int g = tid >> 4, lane16 = tid & 15;

  const float4* src = (const float4*)(z_seq + ((size_t)t * BB + b0) * DG);
  if (tid < 8 * DG / 4) ((float4*)zs)[tid] = src[tid];
  __syncthreads();

#pragma unroll 2
  for (int p = 0; p < 12; ++p) {
    const int r = p * 32 + g;
    const float4* wr = (const float4*)(W_g + (size_t)r * DG);
    float4 w[3];
#pragma unroll
    for (int c = 0; c < 3; ++c) w[c] = wr[lane16 + 16 * c];
    float acc[8];
#pragma unroll
    for (int bb = 0; bb < 8; ++bb) acc[bb] = 0.f;
#pragma unroll
    for (int bb = 0; bb < 8; ++bb) {
      const float4* zz = (const float4*)(zs + bb * DG);
#pragma unroll
      for (int c = 0; c < 3; ++c) {
        float4 z = zz[lane16 + 16 * c];
        acc[bb] = fmaf(w[c].x, z.x, acc[bb]);
        acc[bb] = fmaf(w[c].y, z.y, acc[bb]);
        acc[bb] = fmaf(w[c].z, z.z, acc[bb]);
        acc[bb] = fmaf(w[c].w, z.w, acc[bb]);
      }
    }
#pragma unroll
    for (int bb = 0; bb < 8; ++bb) {
      acc[bb] += __shfl_xor(acc[bb], 8, 64);
      acc[bb] += __shfl_xor(acc[bb], 4, 64);
      acc[bb] += __shfl_xor(acc[bb], 2, 64);
      acc[bb] += __shfl_xor(acc[bb], 1, 64);
    }
    if (lane16 == 0) {
      float bh = b_h[r];
#pragma unroll
      for (int bb = 0; bb < 8; ++bb)
        XZ[((size_t)t * BB + b0 + bb) * DH + r] = acc[bb] + bh;
    }
  }
}

// ====================== FALLBACK (ws too small; not expected) ======================
__global__ __launch_bounds__(384) void fw_rnn_basic(
    const float* __restrict__ z_seq, const float* __restrict__ W_h,
    const float* __restrict__ W_g, const float* __restrict__ b_h,
    const float* __restrict__ ln_g, const float* __restrict__ ln_b,
    const float* __restrict__ alpha_fw, float* __restrict__ out)
{
  __shared__ float hist[NSTEP * DH];
  __shared__ float hs[DH];
  __shared__ float zsh[DG];
  __shared__ float wlamS[NSTEP];
  __shared__ float carr[NSTEP];
  __shared__ float red[6 * 3];

  const int tid = threadIdx.x, b = blockIdx.x;
  const int lane = tid & 63, wv = tid >> 6;
  const float bh_i = b_h[tid], g_i = ln_g[tid], be_i = ln_b[tid];
  const float af = alpha_fw[0];
  const float kk = (af >= 0.f) ? (1.f + log1pf(expf(af)))
                               : (1.f / (1.f + log1pf(expf(-af))));
  const float invD = 1.0f / (float)DH;

  for (int t = 0; t <= NSTEP; ++t) {
    if (tid < DG / 4)
      ((float4*)zsh)[tid] =
          ((const float4*)(z_seq + ((size_t)t * BB + b) * DG))[tid];
    __syncthreads();
    float hb = bh_i;
    {
      const float4* wg4 = (const float4*)(W_g + (size_t)tid * DG);
      const float4* z4 = (const float4*)zsh;
      for (int j = 0; j < DG / 4; ++j) {
        float4 w = wg4[j], z = z4[j];
        hb = fmaf(w.x, z.x, hb); hb = fmaf(w.y, z.y, hb);
        hb = fmaf(w.z, z.z, hb); hb = fmaf(w.w, z.w, hb);
      }
    }
    if (t > 0) {
      const float4* wh4 = (const float4*)(W_h + (size_t)tid * DH);
      const float4* hp4 = (const float4*)(hist + (size_t)(t - 1) * DH);
      for (int j = 0; j < DH / 4; ++j) {
        float4 w = wh4[j], h = hp4[j];
        hb = fmaf(w.x, h.x, hb); hb = fmaf(w.y, h.y, hb);
        hb = fmaf(w.z, h.z, hb); hb = fmaf(w.w, h.w, hb);
      }
    }
    float v0 = hb, v1 = hb * hb;
#pragma unroll
    for (int off = 32; off; off >>= 1) {
      v0 += __shfl_xor(v0, off, 64); v1 += __shfl_xor(v1, off, 64);
    }
    if (lane == 0) { red[wv * 3] = v0; red[wv * 3 + 1] = v1; }
    __syncthreads();
    float S1 = 0, S2 = 0;
    for (int w = 0; w < 6; ++w) { S1 += red[w * 3]; S2 += red[w * 3 + 1]; }
    float m = S1 * invD, var = S2 * invD - m * m;
    float hv = fmaxf((hb - m) * rsqrtf(var + 1e-5f) * g_i + be_i, 0.f);
    hs[tid] = hv;
    __syncthreads();
    int hlen = (t == NSTEP) ? NSTEP : t;
    if (hlen > 0) {
      for (int s = 0; s < SETI; ++s) {
        if (tid < hlen) {
          float p = 0.f;
          for (int j = 0; j < DH; ++j)
            p = fmaf(hist[(size_t)tid * DH + j], hs[j], p);
          carr[tid] = p * wlamS[tid];
        }
        __syncthreads();
        float ah = 0.f;
        for (int tau = 0; tau < hlen; ++tau)
          ah = fmaf(carr[tau], hist[(size_t)tau * DH + tid], ah);
        float w0 = hv * ah, w1 = hv * hv, w2 = ah * ah;
#pragma unroll
        for (int off = 32; off; off >>= 1) {
          w0 += __shfl_xor(w0, off, 64);
          w1 += __shfl_xor(w1, off, 64);
          w2 += __shfl_xor(w2, off, 64);
        }
        if (lane == 0) {
          red[wv * 3] = w0; red[wv * 3 + 1] = w1; red[wv * 3 + 2] = w2;
        }
        __syncthreads();
        float T0 = 0, T1 = 0, T2 = 0;
        for (int w = 0; w < 6; ++w) {
          T0 += red[w * 3]; T1 += red[w * 3 + 1]; T2 += red[w * 3 + 2];
        }
        float xv;
        if (t < NSTEP) {
          float n1 = fmaxf(sqrtf(T1), 1e-6f), n2 = fmaxf(sqrtf(T2), 1e-6f);
          float R = fminf(fmaxf(T0 / (n1 * n2), 0.f), 1.f);
          float a = 1.f - powf(1.f - R, kk);
          xv = (1.f - a * a) * hb + a * ah;
        } else {
          xv = hb + ah;
        }
        __syncthreads();
        float u0 = xv, u1 = xv * xv;
#pragma unroll
        for (int off = 32; off; off >>= 1) {
          u0 += __shfl_xor(u0, off, 64); u1 += __shfl_xor(u1, off, 64);
        }
        if (lane == 0) { red[wv * 3] = u0; red[wv * 3 + 1] = u1; }
        __syncthreads();
        float X1 = 0, X2 = 0;
        for (int w = 0; w < 6; ++w) { X1 += red[w * 3]; X2 += red[w * 3 + 1]; }
        float mm = X1 * invD, vv = X2 * invD - mm * mm;
        hv = fmaxf((xv - mm) * rsqrtf(vv + 1e-5f) * g_i + be_i, 0.f);
        hs[tid] = hv;
        __syncthreads();
      }
    }
    if (t < NSTEP) {
      hist[(size_t)t * DH + tid] = hv;
      if (tid < t) wlamS[tid] *= 0.9f;
      if (tid == t) wlamS[tid] = 0.5f;
      __syncthreads();
    } else {
      out[(size_t)b * DH + tid] = hv;
    }
  }
}

extern "C" void kernel_launch(void* const* d_in, const int* in_sizes, int n_in,
                              void* d_out, int out_size, void* d_ws, size_t ws_size,
                              hipStream_t stream) {
  const float* z_seq    = (const float*)d_in[0];
  const float* W_h      = (const float*)d_in[1];
  const float* W_g      = (const float*)d_in[2];
  const float* b_h      = (const float*)d_in[3];
  const float* ln_g     = (const float*)d_in[4];
  const float* ln_b     = (const float*)d_in[5];
  const float* alpha_fw = (const float*)d_in[6];
  float* out = (float*)d_out;

  const size_t nXZ = (size_t)TT * BB * DH;   // 1769472 fp32
  const size_t nWp = (size_t)DG * DH;        // 73728 uints
  const size_t need = nXZ * sizeof(float) + nWp * sizeof(unsigned);  // ~7.37MB

  if (ws_size >= need) {
    float* XZ = (float*)d_ws;
    unsigned* Wp = (unsigned*)((char*)d_ws + nXZ * sizeof(float));
    pack_w_kernel<<<dim3((int)((nWp + 255) / 256)), dim3(256), 0, stream>>>(
        W_h, Wp);
    xz_kernel<<<dim3(TT, BB / 8), dim3(512), 0, stream>>>(z_seq, W_g, b_h, XZ);
    fw_rnn_v8<<<dim3(BB), dim3(NT), 0, stream>>>(
        XZ, Wp, ln_g, ln_b, alpha_fw, out);
  } else {
    fw_rnn_basic<<<dim3(BB), dim3(NT), 0, stream>>>(
        z_seq, W_h, W_g, b_h, ln_g, ln_b, alpha_fw, out);
  }
}